// Round 1
// baseline (34.209 us; speedup 1.0000x reference)
//
#include <hip/hip_runtime.h>

#define BATCH 2048
#define INF_  512
#define OUTF  256

// async global->LDS, 16B per lane; dst must be wave-uniform base (+lane*16 by HW)
__device__ __forceinline__ void gload16(const float* src, float* dst_lds) {
  __builtin_amdgcn_global_load_lds((const __attribute__((address_space(1))) void*)src,
                                   (__attribute__((address_space(3))) void*)dst_lds,
                                   16, 0, 0);
}

#define MAX3(d, s1, s2) asm("v_max3_f32 %0, %0, %1, %2" : "+v"(d) : "v"(s1), "v"(s2))

// Block: 256 threads = 4 waves (2x2), tile 128 rows x 128 cols, per-thread 8x8.
// A tile in LDS: [128][32] f32, XOR-swizzled: granule(m,kq) = m*8 + (kq ^ ((m>>3)&7))
// B tile in LDS: [32][128] f32, linear (reads are broadcast + 2-way conflict = free)
__global__ __launch_bounds__(256) void crisp_partial(const float* __restrict__ M,
                                                     const float* __restrict__ W,
                                                     float* __restrict__ part,
                                                     int kper) {
  __shared__ __align__(16) float lsA[2][128 * 32];
  __shared__ __align__(16) float lsB[2][32 * 128];

  const int tid    = threadIdx.x;
  const int lane   = tid & 63;
  const int w      = tid >> 6;      // wave id 0..3
  const int mg     = (lane >> 3) & 7;
  const int og     = lane & 7;
  const int wave_m = w >> 1;        // 0..1
  const int wave_o = w & 1;         // 0..1

  const int row0 = blockIdx.y * 128;
  const int col0 = blockIdx.x * 128;
  const int kb0  = blockIdx.z * kper;

  float acc[8][8];
#pragma unroll
  for (int r = 0; r < 8; r++)
#pragma unroll
    for (int c = 0; c < 8; c++) acc[r][c] = -1e30f;

  const int T = kper >> 5;  // BK = 32

  auto stage = [&](int buf, int kb) {
#pragma unroll
    for (int i = 0; i < 4; i++) {
      // A: 1024 granules of 16B. granule p holds A[m][4*kq..+3],
      // m = p>>3, kq = (p&7) ^ ((p>>6)&7)  (inverse of the read-side XOR swizzle)
      int p  = w * 256 + i * 64 + lane;
      int m  = p >> 3;
      int kq = (p & 7) ^ ((p >> 6) & 7);
      const float* srcA = M + (size_t)(row0 + m) * INF_ + kb + kq * 4;
      gload16(srcA, &lsA[buf][(w * 256 + i * 64) * 4]);

      // B: linear. granule p holds W[kb + (p>>5)][col0 + 4*(p&31) .. +3]
      int k = p >> 5;
      int c = p & 31;
      const float* srcB = W + (size_t)(kb + k) * OUTF + col0 + c * 4;
      gload16(srcB, &lsB[buf][(w * 256 + i * 64) * 4]);
    }
  };

  auto compute = [&](int buf) {
    const float* As = lsA[buf];
    const float* Bs = lsB[buf];
    const int mrow0 = wave_m * 64 + mg * 8;
    const int obase = wave_o * 64 + og * 8;
#pragma unroll 2
    for (int kq = 0; kq < 8; kq++) {
      float a[8][4];
#pragma unroll
      for (int r = 0; r < 8; r++) {
        // swizzled read: byte = m*128 + ((kq^mg)<<4); in floats: m*32 + ((kq^mg)<<2)
        float4 v = *reinterpret_cast<const float4*>(
            &As[(mrow0 + r) * 32 + ((kq ^ mg) << 2)]);
        a[r][0] = v.x; a[r][1] = v.y; a[r][2] = v.z; a[r][3] = v.w;
      }
      float bb[4][8];
#pragma unroll
      for (int j = 0; j < 4; j++) {
#pragma unroll
        for (int h = 0; h < 2; h++) {
          float4 v = *reinterpret_cast<const float4*>(
              &Bs[(kq * 4 + j) * 128 + obase + h * 4]);
          bb[j][h * 4 + 0] = v.x; bb[j][h * 4 + 1] = v.y;
          bb[j][h * 4 + 2] = v.z; bb[j][h * 4 + 3] = v.w;
        }
      }
#pragma unroll
      for (int r = 0; r < 8; r++)
#pragma unroll
        for (int c = 0; c < 8; c++) {
          float t0 = fminf(a[r][0], bb[0][c]);
          float t1 = fminf(a[r][1], bb[1][c]);
          float t2 = fminf(a[r][2], bb[2][c]);
          float t3 = fminf(a[r][3], bb[3][c]);
          MAX3(acc[r][c], t0, t1);
          MAX3(acc[r][c], t2, t3);
        }
    }
  };

  stage(0, kb0);
  asm volatile("s_waitcnt vmcnt(0)" ::: "memory");
  __syncthreads();

  for (int t = 0; t < T; ++t) {
    if (t + 1 < T) stage((t + 1) & 1, kb0 + (t + 1) * 32);  // async prefetch
    compute(t & 1);
    asm volatile("s_waitcnt vmcnt(0)" ::: "memory");
    __syncthreads();
  }

  float* pout = part + (size_t)blockIdx.z * (BATCH * OUTF);
  const int orow = row0 + wave_m * 64 + mg * 8;
  const int ocol = col0 + wave_o * 64 + og * 8;
#pragma unroll
  for (int r = 0; r < 8; r++) {
    float4 v0 = make_float4(acc[r][0], acc[r][1], acc[r][2], acc[r][3]);
    float4 v1 = make_float4(acc[r][4], acc[r][5], acc[r][6], acc[r][7]);
    *reinterpret_cast<float4*>(&pout[(size_t)(orow + r) * OUTF + ocol])     = v0;
    *reinterpret_cast<float4*>(&pout[(size_t)(orow + r) * OUTF + ocol + 4]) = v1;
  }
}

__global__ __launch_bounds__(256) void crisp_combine(const float* __restrict__ part,
                                                     float* __restrict__ out, int KS) {
  int i = (blockIdx.x * 256 + threadIdx.x) * 4;
  float4 v = *reinterpret_cast<const float4*>(&part[i]);
  for (int ks = 1; ks < KS; ++ks) {
    float4 u = *reinterpret_cast<const float4*>(&part[(size_t)ks * (BATCH * OUTF) + i]);
    v.x = fmaxf(v.x, u.x); v.y = fmaxf(v.y, u.y);
    v.z = fmaxf(v.z, u.z); v.w = fmaxf(v.w, u.w);
  }
  *reinterpret_cast<float4*>(&out[i]) = v;
}

extern "C" void kernel_launch(void* const* d_in, const int* in_sizes, int n_in,
                              void* d_out, int out_size, void* d_ws, size_t ws_size,
                              hipStream_t stream) {
  const float* M = (const float*)d_in[0];
  const float* W = (const float*)d_in[1];
  float* out = (float*)d_out;

  const size_t plane = (size_t)BATCH * OUTF * sizeof(float);
  int KS = 1;
  if      (ws_size >= 8 * plane) KS = 8;
  else if (ws_size >= 4 * plane) KS = 4;
  else if (ws_size >= 2 * plane) KS = 2;

  float* target = (KS > 1) ? (float*)d_ws : out;
  dim3 grid(OUTF / 128, BATCH / 128, KS);
  crisp_partial<<<grid, 256, 0, stream>>>(M, W, target, INF_ / KS);
  if (KS > 1) {
    crisp_combine<<<(BATCH * OUTF / 4) / 256, 256, 0, stream>>>((const float*)d_ws, out, KS);
  }
}